// Round 4
// baseline (496.482 us; speedup 1.0000x reference)
//
#include <hip/hip_runtime.h>
#include <hip/hip_bf16.h>
#include <math.h>

// out = (M + sum_{s=1..6} P_s)/sqrt(7), P_s = M*P_{s-1}/d_s, P_0 = M.
// One 256-thread block per 64x64 matrix; wave w owns COLUMN strip [16w,16w+16).
// A = M in registers (bf16 hi/lo, 64 VGPR), constant over stages. Stage
// transition C-layout -> B-layout via 16 ds_bpermute + cndmask (verified in
// R3); no LDS round trip in the main loop. Split precision by TRUNCATION:
// hi = x&0xffff0000 (residual exact), packed pairwise with v_perm_b32 —
// ~6 VALU ops per value pair vs ~32 for RNE f2bf packing. Product =
// Ahi*Bhi + Ahi*Blo + Alo*Bhi (fp32 MFMA accum), rep error ~2^-16.

#define RDIM 64
#define MSTR 68   // fp32 row stride: float4-aligned, 2-way-free bank pattern

using bf16x8 = __attribute__((ext_vector_type(8))) short;
using f32x4  = __attribute__((ext_vector_type(4))) float;

union FU { float f; unsigned u; };
static __device__ __forceinline__ unsigned fbits(float x) { FU v; v.f = x; return v.u; }
static __device__ __forceinline__ float ubits(unsigned x) { FU v; v.u = x; return v.f; }

// pack bf16-trunc(a0) into low half, bf16-trunc(a1) into high half (hd);
// same for the exact residuals (ld).
static __device__ __forceinline__ void split2(float a0, float a1,
                                              unsigned& hd, unsigned& ld) {
    const unsigned SEL = 0x07060302u;     // {a1[31:16], a0[31:16]}
    unsigned u0 = fbits(a0), u1 = fbits(a1);
    hd = __builtin_amdgcn_perm(u1, u0, SEL);
    float r0 = a0 - ubits(u0 & 0xffff0000u);   // exact
    float r1 = a1 - ubits(u1 & 0xffff0000u);
    ld = __builtin_amdgcn_perm(fbits(r1), fbits(r0), SEL);
}

struct Decays { float inv[8]; };

#define MFMA(a, b, c) __builtin_amdgcn_mfma_f32_16x16x32_bf16(a, b, c, 0, 0, 0)

__global__ __launch_bounds__(256, 4) void power_series_kernel(
        const float* __restrict__ M, float* __restrict__ out, Decays dec) {
    __shared__ float Ms[RDIM][MSTR];   // 17.4 KB

    const int tid  = threadIdx.x;
    const int w    = tid >> 6;        // wave: column strip [16w, 16w+16)
    const int lane = tid & 63;
    const int q    = lane >> 4;       // quad 0..3
    const int l    = lane & 15;

    const float* Mg = M   + (size_t)blockIdx.x * (RDIM * RDIM);
    float*       Og = out + (size_t)blockIdx.x * (RDIM * RDIM);

    // ---- stage M into LDS (coalesced float4)
    {
        const float4* Mg4 = reinterpret_cast<const float4*>(Mg);
        #pragma unroll
        for (int v = 0; v < 4; ++v) {
            int e = tid + 256 * v;
            float4 x = Mg4[e];
            int row = (e * 4) >> 6, col = (e * 4) & 63;
            *reinterpret_cast<float4*>(&Ms[row][col]) = x;
        }
    }
    __syncthreads();

    union V8 { unsigned d[4]; bf16x8 v; };

    // ---- A frags (constant): lane holds A[m=16t+l][k=32kb+8q+j], j=0..7
    bf16x8 amhi[4][2], amlo[4][2];
    #pragma unroll
    for (int t = 0; t < 4; ++t) {
        #pragma unroll
        for (int kb = 0; kb < 2; ++kb) {
            const float* src = &Ms[16 * t + l][32 * kb + 8 * q];   // 16B-aligned
            float4 x0 = *reinterpret_cast<const float4*>(src);
            float4 x1 = *reinterpret_cast<const float4*>(src + 4);
            float xs[8] = {x0.x, x0.y, x0.z, x0.w, x1.x, x1.y, x1.z, x1.w};
            V8 hv, lv;
            #pragma unroll
            for (int dd = 0; dd < 4; ++dd)
                split2(xs[2 * dd], xs[2 * dd + 1], hv.d[dd], lv.d[dd]);
            amhi[t][kb] = hv.v; amlo[t][kb] = lv.v;
        }
    }

    // ---- B frags of P0 = M: lane holds B[k=32kb+8q+j][n=16w+l]
    bf16x8 pbhi[2], pblo[2];
    #pragma unroll
    for (int kb = 0; kb < 2; ++kb) {
        float xs[8];
        #pragma unroll
        for (int jj = 0; jj < 8; ++jj) {
            int j = (jj + 2 * q) & 7;           // stagger -> spread banks
            xs[j] = Ms[32 * kb + 8 * q + j][16 * w + l];
        }
        V8 hv, lv;
        #pragma unroll
        for (int dd = 0; dd < 4; ++dd)
            split2(xs[2 * dd], xs[2 * dd + 1], hv.d[dd], lv.d[dd]);
        pbhi[kb] = hv.v; pblo[kb] = lv.v;
    }

    // ---- bpermute source addresses (byte addr = srclane*4) — verified R3
    const int sA    = 2 * (q & 1) + (q >> 1);
    const int addrA = ((sA << 4) + l) << 2;
    const int addrB = ((((sA ^ 1)) << 4) + l) << 2;
    const int qlo   = q & 1;
    const int qhi   = q >> 1;

    f32x4 acc[4];
    #pragma unroll
    for (int t = 0; t < 4; ++t) acc[t] = (f32x4){0.f, 0.f, 0.f, 0.f};

    #pragma unroll
    for (int s = 1; s <= 6; ++s) {
        const float inv = dec.inv[s];
        f32x4 c[4];
        unsigned pdh[4][2], pdl[4][2];
        V8 nh[2], nl[2];
        #pragma unroll
        for (int kb = 0; kb < 2; ++kb) {
            #pragma unroll
            for (int tt = 0; tt < 2; ++tt) {
                int t = 2 * kb + tt;
                f32x4 cc = (f32x4){0.f, 0.f, 0.f, 0.f};
                cc = MFMA(amhi[t][0], pbhi[0], cc);
                cc = MFMA(amhi[t][1], pbhi[1], cc);
                cc = MFMA(amhi[t][0], pblo[0], cc);
                cc = MFMA(amhi[t][1], pblo[1], cc);
                cc = MFMA(amlo[t][0], pbhi[0], cc);
                cc = MFMA(amlo[t][1], pbhi[1], cc);
                c[t] = cc;
            }
            if (s < 6) {
                // pack P_s (scaled): pd[t][h] = rows 16t+4q+2h,+1 of col 16w+l
                #pragma unroll
                for (int tt = 0; tt < 2; ++tt) {
                    int t = 2 * kb + tt;
                    #pragma unroll
                    for (int h = 0; h < 2; ++h) {
                        float a0 = c[t][2 * h] * inv, a1 = c[t][2 * h + 1] * inv;
                        acc[t][2 * h] += a0; acc[t][2 * h + 1] += a1;
                        split2(a0, a1, pdh[t][h], pdl[t][h]);
                    }
                }
                // C->B transform within l-groups (overlaps next kb's MFMAs)
                #pragma unroll
                for (int h = 0; h < 2; ++h) {
                    int zA = qlo ? (int)pdh[2 * kb + 1][h] : (int)pdh[2 * kb][h];
                    int zB = qlo ? (int)pdh[2 * kb][h]     : (int)pdh[2 * kb + 1][h];
                    int rA = __builtin_amdgcn_ds_bpermute(addrA, zA);
                    int rB = __builtin_amdgcn_ds_bpermute(addrB, zB);
                    nh[kb].d[h]     = qhi ? rB : rA;
                    nh[kb].d[2 + h] = qhi ? rA : rB;
                    zA = qlo ? (int)pdl[2 * kb + 1][h] : (int)pdl[2 * kb][h];
                    zB = qlo ? (int)pdl[2 * kb][h]     : (int)pdl[2 * kb + 1][h];
                    rA = __builtin_amdgcn_ds_bpermute(addrA, zA);
                    rB = __builtin_amdgcn_ds_bpermute(addrB, zB);
                    nl[kb].d[h]     = qhi ? rB : rA;
                    nl[kb].d[2 + h] = qhi ? rA : rB;
                }
            }
        }
        if (s < 6) {
            pbhi[0] = nh[0].v; pbhi[1] = nh[1].v;
            pblo[0] = nl[0].v; pblo[1] = nl[1].v;
        } else {
            #pragma unroll
            for (int t = 0; t < 4; ++t)
                #pragma unroll
                for (int r = 0; r < 4; ++r)
                    acc[t][r] += c[t][r] * inv;
        }
    }

    // ---- epilogue: out = (M + acc)/sqrt(7), coalesced via LDS round trip.
    // Each thread reads exactly the cells it later writes (bijection), so no
    // barrier needed between its own read and write; one barrier protects
    // other waves' earlier arbitrary-location reads of Ms.
    const float oscale = 0.3779644730092272f;   // 1/sqrt(7)
    float o[4][4];
    #pragma unroll
    for (int t = 0; t < 4; ++t)
        #pragma unroll
        for (int r = 0; r < 4; ++r)
            o[t][r] = (acc[t][r] + Ms[16 * t + 4 * q + r][16 * w + l]) * oscale;
    __syncthreads();
    #pragma unroll
    for (int t = 0; t < 4; ++t)
        #pragma unroll
        for (int r = 0; r < 4; ++r)
            Ms[16 * t + 4 * q + r][16 * w + l] = o[t][r];
    __syncthreads();
    {
        float4* Og4 = reinterpret_cast<float4*>(Og);
        #pragma unroll
        for (int v = 0; v < 4; ++v) {
            int e = tid + 256 * v;
            int row = (e * 4) >> 6, col = (e * 4) & 63;
            Og4[e] = *reinterpret_cast<const float4*>(&Ms[row][col]);
        }
    }
}

extern "C" void kernel_launch(void* const* d_in, const int* in_sizes, int n_in,
                              void* d_out, int out_size, void* d_ws, size_t ws_size,
                              hipStream_t stream) {
    const float* M = (const float*)d_in[0];
    float* out = (float*)d_out;
    const int nmat = in_sizes[0] / (RDIM * RDIM);   // 8192

    static const double V[7] = {1.0, 64.0, 4104.0, 263696.0, 17021060.0,
                                1104218816.0, 72260728960.0};
    Decays dec;
    dec.inv[0] = 1.0f;
    for (int i = 1; i < 7; ++i) dec.inv[i] = (float)(1.0 / sqrt(V[i] / V[i - 1]));
    dec.inv[7] = 0.0f;

    power_series_kernel<<<dim3(nmat), dim3(256), 0, stream>>>(M, out, dec);
}